// Round 12
// baseline (244.557 us; speedup 1.0000x reference)
//
#include <hip/hip_runtime.h>

// 3-layer GAT (PyG GATConv) on MI355X.
// CSR build via two-level counting sort — NO global atomics:
//   A: per-block LDS histogram over coarse buckets (64 nodes each),
//      layer-1 GEMM rides on even blocks (heterogeneous, LDS union).
//   scan: 3-pass exclusive scan of the (bucket x block) matrix.
//   C: re-read chunk, LDS returning-atomic cursors -> scatter PACKED
//      (src | (dst&63)<<17) 4-byte records into bucket regions.
//   D: one block per bucket: LDS 64-hist + scan -> rowst + esrc.
// Layers: gemm_att (micro-tiled LDS GEMM, bf16 H epilogue) -> gat_aggr
// (fused softmax + gather over bf16 H, LDS edge stash; pass-3 uses
// 16-slot batches with an 8-slot tail variant — deg~16 made fixed
// 16-batches waste ~33% of gather/FMA issue, R11).

constexpr int BLOCK = 256;
constexpr int NBLK = 1024;   // hist/scatter blocks (chunked edge ownership)
constexpr int BSH = 6;       // 64 nodes per bucket
constexpr int MAXNB = 1600;  // max buckets (n <= 102400)

__device__ __forceinline__ float llrelu(float x) { return x >= 0.f ? x : 0.2f * x; }

__device__ __forceinline__ unsigned short f2bf(float f) {
    unsigned int u = __float_as_uint(f);
    u += 0x7FFFu + ((u >> 16) & 1u);  // round-to-nearest-even
    return (unsigned short)(u >> 16);
}
__device__ __forceinline__ float bf2f(unsigned short h) {
    return __uint_as_float((unsigned int)h << 16);
}

// ---------- GEMM body (H bf16 + attention dots), LDS provided by caller ----------
template <int FIN, int FOUT, bool RELU_IN>
__device__ __forceinline__ void gemm_att_body(
    const float* __restrict__ X, const float* __restrict__ W,
    const float* __restrict__ asrc, const float* __restrict__ adst,
    unsigned short* __restrict__ H, float* __restrict__ Ssrc,
    float* __restrict__ Sdst, int n, int gblk, float* Xs, float* Ws) {
    constexpr int CG = FOUT / 4;
    constexpr int NG = BLOCK / CG;
    constexpr int TN = NG * 4;
    constexpr int S = FIN + 4;

    int tid = threadIdx.x;
    int n0_blk = gblk * TN;

    for (int t = tid; t < FIN * FOUT / 4; t += BLOCK) {
        float4 v = ((const float4*)W)[t];
        *(float4*)&Ws[t * 4] = v;
    }
    constexpr int RW = FIN / 4;
    for (int t = tid; t < TN * RW; t += BLOCK) {
        int r = t / RW, c = t % RW;
        int gr = n0_blk + r;
        if (gr >= n) gr = n - 1;
        float4 v = ((const float4*)(X + (size_t)gr * FIN))[c];
        if (RELU_IN) {
            v.x = fmaxf(v.x, 0.f); v.y = fmaxf(v.y, 0.f);
            v.z = fmaxf(v.z, 0.f); v.w = fmaxf(v.w, 0.f);
        }
        *(float4*)&Xs[r * S + c * 4] = v;
    }
    __syncthreads();

    int tx = tid % CG, ty = tid / CG;
    int c0 = tx * 4, nloc = ty * 4;

    float acc[4][4];
#pragma unroll
    for (int i = 0; i < 4; ++i)
#pragma unroll
        for (int j = 0; j < 4; ++j) acc[i][j] = 0.f;

#pragma unroll 2
    for (int kc = 0; kc < FIN / 4; ++kc) {
        float4 xv[4], wv[4];
#pragma unroll
        for (int i = 0; i < 4; ++i) xv[i] = *(const float4*)&Xs[(nloc + i) * S + kc * 4];
#pragma unroll
        for (int kk = 0; kk < 4; ++kk) wv[kk] = *(const float4*)&Ws[(kc * 4 + kk) * FOUT + c0];
#pragma unroll
        for (int i = 0; i < 4; ++i) {
            float xi0 = xv[i].x, xi1 = xv[i].y, xi2 = xv[i].z, xi3 = xv[i].w;
            acc[i][0] = fmaf(xi0, wv[0].x, acc[i][0]);
            acc[i][1] = fmaf(xi0, wv[0].y, acc[i][1]);
            acc[i][2] = fmaf(xi0, wv[0].z, acc[i][2]);
            acc[i][3] = fmaf(xi0, wv[0].w, acc[i][3]);
            acc[i][0] = fmaf(xi1, wv[1].x, acc[i][0]);
            acc[i][1] = fmaf(xi1, wv[1].y, acc[i][1]);
            acc[i][2] = fmaf(xi1, wv[1].z, acc[i][2]);
            acc[i][3] = fmaf(xi1, wv[1].w, acc[i][3]);
            acc[i][0] = fmaf(xi2, wv[2].x, acc[i][0]);
            acc[i][1] = fmaf(xi2, wv[2].y, acc[i][1]);
            acc[i][2] = fmaf(xi2, wv[2].z, acc[i][2]);
            acc[i][3] = fmaf(xi2, wv[2].w, acc[i][3]);
            acc[i][0] = fmaf(xi3, wv[3].x, acc[i][0]);
            acc[i][1] = fmaf(xi3, wv[3].y, acc[i][1]);
            acc[i][2] = fmaf(xi3, wv[3].z, acc[i][2]);
            acc[i][3] = fmaf(xi3, wv[3].w, acc[i][3]);
        }
    }

    float4 as4 = *(const float4*)&asrc[c0];
    float4 ad4 = *(const float4*)&adst[c0];

#pragma unroll
    for (int i = 0; i < 4; ++i) {
        int node = n0_blk + nloc + i;
        bool ok = node < n;
        if (ok) {
            ushort4 hb;
            hb.x = f2bf(acc[i][0]); hb.y = f2bf(acc[i][1]);
            hb.z = f2bf(acc[i][2]); hb.w = f2bf(acc[i][3]);
            *(ushort4*)&H[(size_t)node * FOUT + c0] = hb;
        }
        float vs = acc[i][0] * as4.x + acc[i][1] * as4.y + acc[i][2] * as4.z + acc[i][3] * as4.w;
        float vd = acc[i][0] * ad4.x + acc[i][1] * ad4.y + acc[i][2] * ad4.z + acc[i][3] * ad4.w;
#pragma unroll
        for (int off = CG / 2; off > 0; off >>= 1) {
            vs += __shfl_xor(vs, off, CG);
            vd += __shfl_xor(vd, off, CG);
        }
        if (tx == 0 && ok) {
            Ssrc[node] = vs;
            Sdst[node] = vd;
        }
    }
}

template <int FIN, int FOUT, bool RELU_IN>
__global__ void gemm_att_kernel(const float* __restrict__ X, const float* __restrict__ W,
                                const float* __restrict__ asrc, const float* __restrict__ adst,
                                unsigned short* __restrict__ H, float* __restrict__ Ssrc,
                                float* __restrict__ Sdst, int n) {
    constexpr int CG = FOUT / 4;
    constexpr int NG = BLOCK / CG;
    constexpr int TN = NG * 4;
    constexpr int S = FIN + 4;
    __shared__ float Xs[TN * S];
    __shared__ float Ws[FIN * FOUT];
    gemm_att_body<FIN, FOUT, RELU_IN>(X, W, asrc, adst, H, Ssrc, Sdst, n, blockIdx.x, Xs, Ws);
}

// ---------- Phase A: coarse histogram (odd blocks) + layer-1 GEMM (even) ----------
__global__ void hist_gemm1_kernel(const float* __restrict__ X, const float* __restrict__ W,
                                  const float* __restrict__ asrc, const float* __restrict__ adst,
                                  unsigned short* __restrict__ H, float* __restrict__ Ssrc,
                                  float* __restrict__ Sdst, int n, int ngemm,
                                  const int* __restrict__ dst, int E, int chunk, int NB,
                                  int* __restrict__ S, float* __restrict__ facc) {
    // LDS union: gemm<64,64> needs 64*68 + 64*64 = 8448 floats; hist needs 1600 ints.
    __shared__ __align__(16) float lds[8448];
    int bid = blockIdx.x;
    if ((bid & 1) == 0) {
        int gb = bid >> 1;
        if (gb >= ngemm) return;
        gemm_att_body<64, 64, false>(X, W, asrc, adst, H, Ssrc, Sdst, n, gb, lds, lds + 64 * 68);
    } else {
        int k = bid >> 1;
        if (k >= NBLK) return;
        int* hist = (int*)lds;
        for (int i = threadIdx.x; i < NB; i += BLOCK) hist[i] = 0;
        if (k == 0 && threadIdx.x < 32) facc[threadIdx.x] = 0.f;
        __syncthreads();
        int start = k * chunk, end = min(E, start + chunk);
        for (int i = start + threadIdx.x; i < end; i += BLOCK)
            atomicAdd(&hist[dst[i] >> BSH], 1);
        __syncthreads();
        for (int b = threadIdx.x; b < NB; b += BLOCK) S[(size_t)b * NBLK + k] = hist[b];
    }
}

// ---------- 3-pass exclusive scan over S[NB*NBLK] ----------
__global__ void scan1_kernel(int* __restrict__ S, int total, int* __restrict__ bsums) {
    __shared__ int s[1024];
    int tid = threadIdx.x;
    int gid = blockIdx.x * 1024 + tid;
    int v = (gid < total) ? S[gid] : 0;
    s[tid] = v;
    for (int off = 1; off < 1024; off <<= 1) {
        __syncthreads();
        int t = (tid >= off) ? s[tid - off] : 0;
        __syncthreads();
        s[tid] += t;
    }
    __syncthreads();
    if (gid < total) S[gid] = s[tid] - v;  // exclusive within block
    if (tid == 1023) bsums[blockIdx.x] = s[tid];
}

// Single-block tiled scan (handles nb > 1024 via carried offset).
__global__ void scan2_kernel(int* __restrict__ bsums, int nb) {
    __shared__ int s[1024];
    __shared__ int carry_s;
    int tid = threadIdx.x;
    if (tid == 0) carry_s = 0;
    __syncthreads();
    for (int base = 0; base < nb; base += 1024) {
        int i = base + tid;
        int v = (i < nb) ? bsums[i] : 0;
        s[tid] = v;
        for (int off = 1; off < 1024; off <<= 1) {
            __syncthreads();
            int t = (tid >= off) ? s[tid - off] : 0;
            __syncthreads();
            s[tid] += t;
        }
        __syncthreads();
        int c = carry_s;
        if (i < nb) bsums[i] = s[tid] - v + c;  // exclusive + carry
        __syncthreads();
        if (tid == 1023) carry_s = c + s[1023];
        __syncthreads();
    }
}

__global__ void scan3_kernel(int* __restrict__ S, const int* __restrict__ bsums, int total) {
    int gid = blockIdx.x * blockDim.x + threadIdx.x;
    if (gid < total) S[gid] += bsums[gid >> 10];
}

// ---------- Phase C: scatter packed records into bucket regions ----------
// Record: src | (dst&63)<<17  (requires n <= 131072; here n = 100000).
__global__ void scatter_kernel(const int* __restrict__ src, const int* __restrict__ dst,
                               int E, int chunk, int NB, const int* __restrict__ S,
                               int* __restrict__ pairs) {
    __shared__ int cursor[MAXNB];
    int k = blockIdx.x;
    for (int b = threadIdx.x; b < NB; b += BLOCK) cursor[b] = S[(size_t)b * NBLK + k];
    __syncthreads();
    int start = k * chunk, end = min(E, start + chunk);
    for (int i = start + threadIdx.x; i < end; i += BLOCK) {
        int d = dst[i], s = src[i];
        int pos = atomicAdd(&cursor[d >> BSH], 1);  // LDS returning atomic
        pairs[pos] = s | ((d & 63) << 17);
    }
}

// ---------- Phase D: per-bucket CSR (rowst + in-bucket dst-sorted esrc) ----------
__global__ void bucket_csr_kernel(const int* __restrict__ pairs, const int* __restrict__ S,
                                  int NB, int n, int E, int* __restrict__ rowst,
                                  int* __restrict__ esrc) {
    __shared__ int cnt[64], excl[64];
    int b = blockIdx.x;
    if (b >= NB) return;
    int base = S[(size_t)b * NBLK];
    int end = (b + 1 < NB) ? S[(size_t)(b + 1) * NBLK] : E;
    int m = end - base;
    if (threadIdx.x < 64) cnt[threadIdx.x] = 0;
    __syncthreads();
    for (int i = threadIdx.x; i < m; i += BLOCK)
        atomicAdd(&cnt[pairs[base + i] >> 17], 1);
    __syncthreads();
    if (threadIdx.x == 0) {
        int run = 0;
        for (int j = 0; j < 64; ++j) { excl[j] = run; run += cnt[j]; }
    }
    __syncthreads();
    int node0 = b << BSH;
    if (threadIdx.x < 64) {
        int node = node0 + threadIdx.x;
        if (node < n) rowst[node] = base + excl[threadIdx.x];
        cnt[threadIdx.x] = excl[threadIdx.x];  // becomes the running cursor
    }
    if (b == NB - 1 && threadIdx.x == 0) rowst[n] = E;
    __syncthreads();
    for (int i = threadIdx.x; i < m; i += BLOCK) {
        int p = pairs[base + i];
        int pos = atomicAdd(&cnt[p >> 17], 1);  // LDS returning atomic
        esrc[base + pos] = p & 0x1FFFF;
    }
}

// ---------- gather-FMA batch (NBATCH = 8 or 16 stash slots) ----------
template <int NBATCH>
__device__ __forceinline__ void gather_fma(const unsigned short* __restrict__ H,
                                           const float* wldsg, const int* ildsg,
                                           int j0, int lane, float& acc) {
    float wv[NBATCH];
    int ix[NBATCH];
#pragma unroll
    for (int q = 0; q < NBATCH / 4; ++q) {
        float4 w = *(const float4*)&wldsg[j0 + q * 4];
        int4 i4 = *(const int4*)&ildsg[j0 + q * 4];
        wv[q * 4 + 0] = w.x; wv[q * 4 + 1] = w.y; wv[q * 4 + 2] = w.z; wv[q * 4 + 3] = w.w;
        ix[q * 4 + 0] = i4.x; ix[q * 4 + 1] = i4.y; ix[q * 4 + 2] = i4.z; ix[q * 4 + 3] = i4.w;
    }
    unsigned short hv[NBATCH];
#pragma unroll
    for (int u = 0; u < NBATCH; ++u) hv[u] = H[(size_t)(unsigned)(ix[u] + lane)];
#pragma unroll
    for (int u = 0; u < NBATCH; ++u) acc = fmaf(wv[u], bf2f(hv[u]), acc);
}

// ---------- fused softmax + gather core ----------
template <int F, int K>
__device__ __forceinline__ float aggr_node_core(
    const unsigned short* __restrict__ H, const float* __restrict__ Ssrc,
    const float* __restrict__ Sdst, const int* __restrict__ row_start,
    const int* __restrict__ esrc, int node, int lane,
    float* wldsg, int* ildsg) {
    constexpr int NS = K * F;
    int rs = row_start[node];
    int deg = row_start[node + 1] - rs;
    float sdi = Sdst[node];
    float selft = llrelu(Ssrc[node] + sdi);

    float wreg[K];
#pragma unroll
    for (int k = 0; k < K; ++k) {
        wldsg[k * F + lane] = 0.f;
        ildsg[k * F + lane] = node * F;
    }

    float m = selft;
#pragma unroll
    for (int k = 0; k < K; ++k) {
        int j = k * F + lane;
        if (j < deg) {
            int s = esrc[rs + j];
            float t = llrelu(Ssrc[s] + sdi);
            ildsg[j] = s * F;
            wreg[k] = t;
            m = fmaxf(m, t);
        }
    }
    for (int j = NS + lane; j < deg; j += F)
        m = fmaxf(m, llrelu(Ssrc[esrc[rs + j]] + sdi));
#pragma unroll
    for (int off = F / 2; off > 0; off >>= 1) m = fmaxf(m, __shfl_xor(m, off, F));

    float selfw = __expf(selft - m);
    float l = (lane == 0) ? selfw : 0.f;
#pragma unroll
    for (int k = 0; k < K; ++k) {
        int j = k * F + lane;
        if (j < deg) {
            float e = __expf(wreg[k] - m);
            wldsg[j] = e;
            l += e;
        }
    }
    for (int j = NS + lane; j < deg; j += F)
        l += __expf(llrelu(Ssrc[esrc[rs + j]] + sdi) - m);
#pragma unroll
    for (int off = F / 2; off > 0; off >>= 1) l += __shfl_xor(l, off, F);
    float winv = 1.f / l;

    // pass 3: full 16-slot batches + 8-slot tail (deg is wave-uniform ->
    // uniform branch; stash pre-init makes any aligned batch safe).
    float acc = selfw * bf2f(H[(size_t)node * F + lane]);
    int nbv = deg < NS ? deg : NS;
    int nb16 = nbv & ~15;
    int j0 = 0;
    for (; j0 < nb16; j0 += 16) gather_fma<16>(H, wldsg, ildsg, j0, lane, acc);
    int rem = nbv - nb16;
    if (rem > 8) gather_fma<16>(H, wldsg, ildsg, j0, lane, acc);
    else if (rem > 0) gather_fma<8>(H, wldsg, ildsg, j0, lane, acc);

    for (int j = NS; j < deg; ++j) {
        int s = esrc[rs + j];
        float wj = __expf(llrelu(Ssrc[s] + sdi) - m);
        acc = fmaf(wj, bf2f(H[(size_t)s * F + lane]), acc);
    }
    return acc * winv;
}

// Standalone aggregation: one node per group, OUT f32 (+bias optional).
template <int F, int K, bool WITH_BIAS>
__global__ void gat_aggr_kernel(const unsigned short* __restrict__ H,
                                const float* __restrict__ Ssrc, const float* __restrict__ Sdst,
                                const int* __restrict__ rowst, const int* __restrict__ esrc,
                                const float* __restrict__ bias, float* __restrict__ OUT, int n) {
    constexpr int GPB = BLOCK / F;
    __shared__ __align__(16) float wlds[GPB][K * F];
    __shared__ __align__(16) int ilds[GPB][K * F];
    int tid = threadIdx.x;
    int grp = tid / F, lane = tid % F;
    int node = blockIdx.x * GPB + grp;
    if (node >= n) return;
    float acc = aggr_node_core<F, K>(H, Ssrc, Sdst, rowst, esrc, node, lane,
                                     wlds[grp], ilds[grp]);
    if (WITH_BIAS) acc += bias[lane];
    OUT[(size_t)node * F + lane] = acc;
}

// Sum OUT3 over nodes into facc[32].
__global__ void mean_kernel(const float* __restrict__ B, float* __restrict__ facc, int n) {
    __shared__ float s[32];
    int lane = threadIdx.x & 31, row = threadIdx.x >> 5;
    float a = 0.f;
    for (int node = blockIdx.x * 8 + row; node < n; node += gridDim.x * 8)
        a += B[(size_t)node * 32 + lane];
    if (threadIdx.x < 32) s[threadIdx.x] = 0.f;
    __syncthreads();
    atomicAdd(&s[lane], a);
    __syncthreads();
    if (threadIdx.x < 32) atomicAdd(&facc[threadIdx.x], s[threadIdx.x]);
}

__global__ void finalize_kernel(const float* __restrict__ facc, const float* __restrict__ b,
                                const float* __restrict__ tdp, const float* __restrict__ cansup,
                                float* __restrict__ out, int n) {
    int f = threadIdx.x;
    if (f < 32) {
        float td = tdp[0] * cansup[0];
        out[f] = (facc[f] / (float)n + b[f]) * td;
    }
}

extern "C" void kernel_launch(void* const* d_in, const int* in_sizes, int n_in,
                              void* d_out, int out_size, void* d_ws, size_t ws_size,
                              hipStream_t stream) {
    const float* x      = (const float*)d_in[0];
    const int* eidx     = (const int*)d_in[1];
    const float* W1     = (const float*)d_in[2];
    const float* as1    = (const float*)d_in[3];
    const float* ad1    = (const float*)d_in[4];
    const float* b1     = (const float*)d_in[5];
    const float* W2     = (const float*)d_in[6];
    const float* as2    = (const float*)d_in[7];
    const float* ad2    = (const float*)d_in[8];
    const float* b2     = (const float*)d_in[9];
    const float* W3     = (const float*)d_in[10];
    const float* as3    = (const float*)d_in[11];
    const float* ad3    = (const float*)d_in[12];
    const float* b3     = (const float*)d_in[13];
    const float* tdp    = (const float*)d_in[14];
    const float* cansup = (const float*)d_in[15];

    const int n = in_sizes[0] / 64;   // 100000 nodes
    const int E = in_sizes[1] / 2;    // 1600000 edges
    const int* srcp = eidx;
    const int* dstp = eidx + E;

    const int NB = (n + 63) >> BSH;           // 1563 buckets
    const int chunk = (E + NBLK - 1) / NBLK;  // edges per hist/scatter block
    const int total = NB * NBLK;              // scan matrix size

    char* ws = (char*)d_ws;
    size_t off = 0;
    auto alloc = [&](size_t bytes) -> void* {
        void* p = ws + off;
        off += (bytes + 255) & ~(size_t)255;
        return p;
    };
    unsigned short* H1 = (unsigned short*)alloc((size_t)n * 64 * sizeof(unsigned short));
    unsigned short* H2 = (unsigned short*)alloc((size_t)n * 32 * sizeof(unsigned short));
    unsigned short* H3 = (unsigned short*)alloc((size_t)n * 32 * sizeof(unsigned short));
    float* B      = (float*)alloc((size_t)n * 64 * sizeof(float));  // f32 layer output
    float* ssA    = (float*)alloc((size_t)n * sizeof(float));
    float* sdA    = (float*)alloc((size_t)n * sizeof(float));
    float* ssB    = (float*)alloc((size_t)n * sizeof(float));
    float* sdB    = (float*)alloc((size_t)n * sizeof(float));
    float* ssC    = (float*)alloc((size_t)n * sizeof(float));
    float* sdC    = (float*)alloc((size_t)n * sizeof(float));
    int*   S      = (int*)alloc((size_t)total * sizeof(int));
    int*   bsums  = (int*)alloc(2048 * sizeof(int));
    int*   rowst  = (int*)alloc((size_t)(n + 1) * sizeof(int));
    int*   esrc   = (int*)alloc((size_t)E * sizeof(int));
    int*   pairs  = (int*)alloc((size_t)E * sizeof(int));
    float* facc   = (float*)alloc(64 * sizeof(float));

    // ---- CSR build (counting sort, no global atomics) + layer-1 GEMM ----
    const int ngemm1 = (n + 63) / 64;
    const int gmax = (ngemm1 > NBLK) ? ngemm1 : NBLK;
    hist_gemm1_kernel<<<2 * gmax, BLOCK, 0, stream>>>(
        x, W1, as1, ad1, H1, ssA, sdA, n, ngemm1, dstp, E, chunk, NB, S, facc);
    int nb1 = (total + 1023) / 1024;
    scan1_kernel<<<nb1, 1024, 0, stream>>>(S, total, bsums);
    scan2_kernel<<<1, 1024, 0, stream>>>(bsums, nb1);
    scan3_kernel<<<(total + 255) / 256, 256, 0, stream>>>(S, bsums, total);
    scatter_kernel<<<NBLK, BLOCK, 0, stream>>>(srcp, dstp, E, chunk, NB, S, pairs);
    bucket_csr_kernel<<<NB, BLOCK, 0, stream>>>(pairs, S, NB, n, E, rowst, esrc);

    // ---- layer 1 aggregation ----
    gat_aggr_kernel<64, 2, true><<<(n + 3) / 4, BLOCK, 0, stream>>>(
        H1, ssA, sdA, rowst, esrc, b1, B, n);

    // ---- layer 2 ----
    gemm_att_kernel<64, 32, true><<<(n + 127) / 128, BLOCK, 0, stream>>>(
        B, W2, as2, ad2, H2, ssB, sdB, n);
    gat_aggr_kernel<32, 4, true><<<(n + 7) / 8, BLOCK, 0, stream>>>(
        H2, ssB, sdB, rowst, esrc, b2, B, n);

    // ---- layer 3 ----
    gemm_att_kernel<32, 32, true><<<(n + 127) / 128, BLOCK, 0, stream>>>(
        B, W3, as3, ad3, H3, ssC, sdC, n);
    gat_aggr_kernel<32, 4, false><<<(n + 7) / 8, BLOCK, 0, stream>>>(
        H3, ssC, sdC, rowst, esrc, nullptr, B, n);
    mean_kernel<<<1024, 256, 0, stream>>>(B, facc, n);
    finalize_kernel<<<1, 64, 0, stream>>>(facc, b3, tdp, cansup, (float*)d_out, n);
}

// Round 13
// 231.943 us; speedup vs baseline: 1.0544x; 1.0544x over previous
//
#include <hip/hip_runtime.h>

// 3-layer GAT (PyG GATConv) on MI355X.
// CSR build via two-level counting sort — NO global atomics:
//   A: per-block LDS histogram over coarse buckets (64 nodes each),
//      layer-1 GEMM rides on even blocks (heterogeneous, LDS union).
//   scan: 3-pass exclusive scan of the (bucket x block) matrix.
//   C: re-read chunk, LDS returning-atomic cursors -> scatter PACKED
//      (src | (dst&63)<<17) 4-byte records into bucket regions.
//   D: one block per bucket: LDS 64-hist + scan -> rowst + esrc.
// NBLK=512 (R12 lesson: 1024 doubles scan-matrix + hist overhead, -15us).
// Layers: gemm_att (micro-tiled LDS GEMM, bf16 H epilogue) -> gat_aggr
// (fused softmax + gather over bf16 H, LDS edge stash; pass-3 uses
// 16-slot batches with an 8-slot tail variant).

constexpr int BLOCK = 256;
constexpr int NBLK = 512;    // hist/scatter blocks (chunked edge ownership)
constexpr int BSH = 6;       // 64 nodes per bucket
constexpr int MAXNB = 1600;  // max buckets (n <= 102400)

__device__ __forceinline__ float llrelu(float x) { return x >= 0.f ? x : 0.2f * x; }

__device__ __forceinline__ unsigned short f2bf(float f) {
    unsigned int u = __float_as_uint(f);
    u += 0x7FFFu + ((u >> 16) & 1u);  // round-to-nearest-even
    return (unsigned short)(u >> 16);
}
__device__ __forceinline__ float bf2f(unsigned short h) {
    return __uint_as_float((unsigned int)h << 16);
}

// ---------- GEMM body (H bf16 + attention dots), LDS provided by caller ----------
template <int FIN, int FOUT, bool RELU_IN>
__device__ __forceinline__ void gemm_att_body(
    const float* __restrict__ X, const float* __restrict__ W,
    const float* __restrict__ asrc, const float* __restrict__ adst,
    unsigned short* __restrict__ H, float* __restrict__ Ssrc,
    float* __restrict__ Sdst, int n, int gblk, float* Xs, float* Ws) {
    constexpr int CG = FOUT / 4;
    constexpr int NG = BLOCK / CG;
    constexpr int TN = NG * 4;
    constexpr int S = FIN + 4;

    int tid = threadIdx.x;
    int n0_blk = gblk * TN;

    for (int t = tid; t < FIN * FOUT / 4; t += BLOCK) {
        float4 v = ((const float4*)W)[t];
        *(float4*)&Ws[t * 4] = v;
    }
    constexpr int RW = FIN / 4;
    for (int t = tid; t < TN * RW; t += BLOCK) {
        int r = t / RW, c = t % RW;
        int gr = n0_blk + r;
        if (gr >= n) gr = n - 1;
        float4 v = ((const float4*)(X + (size_t)gr * FIN))[c];
        if (RELU_IN) {
            v.x = fmaxf(v.x, 0.f); v.y = fmaxf(v.y, 0.f);
            v.z = fmaxf(v.z, 0.f); v.w = fmaxf(v.w, 0.f);
        }
        *(float4*)&Xs[r * S + c * 4] = v;
    }
    __syncthreads();

    int tx = tid % CG, ty = tid / CG;
    int c0 = tx * 4, nloc = ty * 4;

    float acc[4][4];
#pragma unroll
    for (int i = 0; i < 4; ++i)
#pragma unroll
        for (int j = 0; j < 4; ++j) acc[i][j] = 0.f;

#pragma unroll 2
    for (int kc = 0; kc < FIN / 4; ++kc) {
        float4 xv[4], wv[4];
#pragma unroll
        for (int i = 0; i < 4; ++i) xv[i] = *(const float4*)&Xs[(nloc + i) * S + kc * 4];
#pragma unroll
        for (int kk = 0; kk < 4; ++kk) wv[kk] = *(const float4*)&Ws[(kc * 4 + kk) * FOUT + c0];
#pragma unroll
        for (int i = 0; i < 4; ++i) {
            float xi0 = xv[i].x, xi1 = xv[i].y, xi2 = xv[i].z, xi3 = xv[i].w;
            acc[i][0] = fmaf(xi0, wv[0].x, acc[i][0]);
            acc[i][1] = fmaf(xi0, wv[0].y, acc[i][1]);
            acc[i][2] = fmaf(xi0, wv[0].z, acc[i][2]);
            acc[i][3] = fmaf(xi0, wv[0].w, acc[i][3]);
            acc[i][0] = fmaf(xi1, wv[1].x, acc[i][0]);
            acc[i][1] = fmaf(xi1, wv[1].y, acc[i][1]);
            acc[i][2] = fmaf(xi1, wv[1].z, acc[i][2]);
            acc[i][3] = fmaf(xi1, wv[1].w, acc[i][3]);
            acc[i][0] = fmaf(xi2, wv[2].x, acc[i][0]);
            acc[i][1] = fmaf(xi2, wv[2].y, acc[i][1]);
            acc[i][2] = fmaf(xi2, wv[2].z, acc[i][2]);
            acc[i][3] = fmaf(xi2, wv[2].w, acc[i][3]);
            acc[i][0] = fmaf(xi3, wv[3].x, acc[i][0]);
            acc[i][1] = fmaf(xi3, wv[3].y, acc[i][1]);
            acc[i][2] = fmaf(xi3, wv[3].z, acc[i][2]);
            acc[i][3] = fmaf(xi3, wv[3].w, acc[i][3]);
        }
    }

    float4 as4 = *(const float4*)&asrc[c0];
    float4 ad4 = *(const float4*)&adst[c0];

#pragma unroll
    for (int i = 0; i < 4; ++i) {
        int node = n0_blk + nloc + i;
        bool ok = node < n;
        if (ok) {
            ushort4 hb;
            hb.x = f2bf(acc[i][0]); hb.y = f2bf(acc[i][1]);
            hb.z = f2bf(acc[i][2]); hb.w = f2bf(acc[i][3]);
            *(ushort4*)&H[(size_t)node * FOUT + c0] = hb;
        }
        float vs = acc[i][0] * as4.x + acc[i][1] * as4.y + acc[i][2] * as4.z + acc[i][3] * as4.w;
        float vd = acc[i][0] * ad4.x + acc[i][1] * ad4.y + acc[i][2] * ad4.z + acc[i][3] * ad4.w;
#pragma unroll
        for (int off = CG / 2; off > 0; off >>= 1) {
            vs += __shfl_xor(vs, off, CG);
            vd += __shfl_xor(vd, off, CG);
        }
        if (tx == 0 && ok) {
            Ssrc[node] = vs;
            Sdst[node] = vd;
        }
    }
}

template <int FIN, int FOUT, bool RELU_IN>
__global__ void gemm_att_kernel(const float* __restrict__ X, const float* __restrict__ W,
                                const float* __restrict__ asrc, const float* __restrict__ adst,
                                unsigned short* __restrict__ H, float* __restrict__ Ssrc,
                                float* __restrict__ Sdst, int n) {
    constexpr int CG = FOUT / 4;
    constexpr int NG = BLOCK / CG;
    constexpr int TN = NG * 4;
    constexpr int S = FIN + 4;
    __shared__ float Xs[TN * S];
    __shared__ float Ws[FIN * FOUT];
    gemm_att_body<FIN, FOUT, RELU_IN>(X, W, asrc, adst, H, Ssrc, Sdst, n, blockIdx.x, Xs, Ws);
}

// ---------- Phase A: coarse histogram (odd blocks) + layer-1 GEMM (even) ----------
__global__ void hist_gemm1_kernel(const float* __restrict__ X, const float* __restrict__ W,
                                  const float* __restrict__ asrc, const float* __restrict__ adst,
                                  unsigned short* __restrict__ H, float* __restrict__ Ssrc,
                                  float* __restrict__ Sdst, int n, int ngemm,
                                  const int* __restrict__ dst, int E, int chunk, int NB,
                                  int* __restrict__ S, float* __restrict__ facc) {
    // LDS union: gemm<64,64> needs 64*68 + 64*64 = 8448 floats; hist needs 1600 ints.
    __shared__ __align__(16) float lds[8448];
    int bid = blockIdx.x;
    if ((bid & 1) == 0) {
        int gb = bid >> 1;
        if (gb >= ngemm) return;
        gemm_att_body<64, 64, false>(X, W, asrc, adst, H, Ssrc, Sdst, n, gb, lds, lds + 64 * 68);
    } else {
        int k = bid >> 1;
        if (k >= NBLK) return;
        int* hist = (int*)lds;
        for (int i = threadIdx.x; i < NB; i += BLOCK) hist[i] = 0;
        if (k == 0 && threadIdx.x < 32) facc[threadIdx.x] = 0.f;
        __syncthreads();
        int start = k * chunk, end = min(E, start + chunk);
        for (int i = start + threadIdx.x; i < end; i += BLOCK)
            atomicAdd(&hist[dst[i] >> BSH], 1);
        __syncthreads();
        for (int b = threadIdx.x; b < NB; b += BLOCK) S[(size_t)b * NBLK + k] = hist[b];
    }
}

// ---------- 3-pass exclusive scan over S[NB*NBLK] ----------
__global__ void scan1_kernel(int* __restrict__ S, int total, int* __restrict__ bsums) {
    __shared__ int s[1024];
    int tid = threadIdx.x;
    int gid = blockIdx.x * 1024 + tid;
    int v = (gid < total) ? S[gid] : 0;
    s[tid] = v;
    for (int off = 1; off < 1024; off <<= 1) {
        __syncthreads();
        int t = (tid >= off) ? s[tid - off] : 0;
        __syncthreads();
        s[tid] += t;
    }
    __syncthreads();
    if (gid < total) S[gid] = s[tid] - v;  // exclusive within block
    if (tid == 1023) bsums[blockIdx.x] = s[tid];
}

// Single-block tiled scan (handles nb > 1024 via carried offset).
__global__ void scan2_kernel(int* __restrict__ bsums, int nb) {
    __shared__ int s[1024];
    __shared__ int carry_s;
    int tid = threadIdx.x;
    if (tid == 0) carry_s = 0;
    __syncthreads();
    for (int base = 0; base < nb; base += 1024) {
        int i = base + tid;
        int v = (i < nb) ? bsums[i] : 0;
        s[tid] = v;
        for (int off = 1; off < 1024; off <<= 1) {
            __syncthreads();
            int t = (tid >= off) ? s[tid - off] : 0;
            __syncthreads();
            s[tid] += t;
        }
        __syncthreads();
        int c = carry_s;
        if (i < nb) bsums[i] = s[tid] - v + c;  // exclusive + carry
        __syncthreads();
        if (tid == 1023) carry_s = c + s[1023];
        __syncthreads();
    }
}

__global__ void scan3_kernel(int* __restrict__ S, const int* __restrict__ bsums, int total) {
    int gid = blockIdx.x * blockDim.x + threadIdx.x;
    if (gid < total) S[gid] += bsums[gid >> 10];
}

// ---------- Phase C: scatter packed records into bucket regions ----------
// Record: src | (dst&63)<<17  (requires n <= 131072; here n = 100000).
__global__ void scatter_kernel(const int* __restrict__ src, const int* __restrict__ dst,
                               int E, int chunk, int NB, const int* __restrict__ S,
                               int* __restrict__ pairs) {
    __shared__ int cursor[MAXNB];
    int k = blockIdx.x;
    for (int b = threadIdx.x; b < NB; b += BLOCK) cursor[b] = S[(size_t)b * NBLK + k];
    __syncthreads();
    int start = k * chunk, end = min(E, start + chunk);
    for (int i = start + threadIdx.x; i < end; i += BLOCK) {
        int d = dst[i], s = src[i];
        int pos = atomicAdd(&cursor[d >> BSH], 1);  // LDS returning atomic
        pairs[pos] = s | ((d & 63) << 17);
    }
}

// ---------- Phase D: per-bucket CSR (rowst + in-bucket dst-sorted esrc) ----------
__global__ void bucket_csr_kernel(const int* __restrict__ pairs, const int* __restrict__ S,
                                  int NB, int n, int E, int* __restrict__ rowst,
                                  int* __restrict__ esrc) {
    __shared__ int cnt[64], excl[64];
    int b = blockIdx.x;
    if (b >= NB) return;
    int base = S[(size_t)b * NBLK];
    int end = (b + 1 < NB) ? S[(size_t)(b + 1) * NBLK] : E;
    int m = end - base;
    if (threadIdx.x < 64) cnt[threadIdx.x] = 0;
    __syncthreads();
    for (int i = threadIdx.x; i < m; i += BLOCK)
        atomicAdd(&cnt[pairs[base + i] >> 17], 1);
    __syncthreads();
    if (threadIdx.x == 0) {
        int run = 0;
        for (int j = 0; j < 64; ++j) { excl[j] = run; run += cnt[j]; }
    }
    __syncthreads();
    int node0 = b << BSH;
    if (threadIdx.x < 64) {
        int node = node0 + threadIdx.x;
        if (node < n) rowst[node] = base + excl[threadIdx.x];
        cnt[threadIdx.x] = excl[threadIdx.x];  // becomes the running cursor
    }
    if (b == NB - 1 && threadIdx.x == 0) rowst[n] = E;
    __syncthreads();
    for (int i = threadIdx.x; i < m; i += BLOCK) {
        int p = pairs[base + i];
        int pos = atomicAdd(&cnt[p >> 17], 1);  // LDS returning atomic
        esrc[base + pos] = p & 0x1FFFF;
    }
}

// ---------- gather-FMA batch (NBATCH = 8 or 16 stash slots) ----------
template <int NBATCH>
__device__ __forceinline__ void gather_fma(const unsigned short* __restrict__ H,
                                           const float* wldsg, const int* ildsg,
                                           int j0, int lane, float& acc) {
    float wv[NBATCH];
    int ix[NBATCH];
#pragma unroll
    for (int q = 0; q < NBATCH / 4; ++q) {
        float4 w = *(const float4*)&wldsg[j0 + q * 4];
        int4 i4 = *(const int4*)&ildsg[j0 + q * 4];
        wv[q * 4 + 0] = w.x; wv[q * 4 + 1] = w.y; wv[q * 4 + 2] = w.z; wv[q * 4 + 3] = w.w;
        ix[q * 4 + 0] = i4.x; ix[q * 4 + 1] = i4.y; ix[q * 4 + 2] = i4.z; ix[q * 4 + 3] = i4.w;
    }
    unsigned short hv[NBATCH];
#pragma unroll
    for (int u = 0; u < NBATCH; ++u) hv[u] = H[(size_t)(unsigned)(ix[u] + lane)];
#pragma unroll
    for (int u = 0; u < NBATCH; ++u) acc = fmaf(wv[u], bf2f(hv[u]), acc);
}

// ---------- fused softmax + gather core ----------
template <int F, int K>
__device__ __forceinline__ float aggr_node_core(
    const unsigned short* __restrict__ H, const float* __restrict__ Ssrc,
    const float* __restrict__ Sdst, const int* __restrict__ row_start,
    const int* __restrict__ esrc, int node, int lane,
    float* wldsg, int* ildsg) {
    constexpr int NS = K * F;
    int rs = row_start[node];
    int deg = row_start[node + 1] - rs;
    float sdi = Sdst[node];
    float selft = llrelu(Ssrc[node] + sdi);

    float wreg[K];
#pragma unroll
    for (int k = 0; k < K; ++k) {
        wldsg[k * F + lane] = 0.f;
        ildsg[k * F + lane] = node * F;
    }

    float m = selft;
#pragma unroll
    for (int k = 0; k < K; ++k) {
        int j = k * F + lane;
        if (j < deg) {
            int s = esrc[rs + j];
            float t = llrelu(Ssrc[s] + sdi);
            ildsg[j] = s * F;
            wreg[k] = t;
            m = fmaxf(m, t);
        }
    }
    for (int j = NS + lane; j < deg; j += F)
        m = fmaxf(m, llrelu(Ssrc[esrc[rs + j]] + sdi));
#pragma unroll
    for (int off = F / 2; off > 0; off >>= 1) m = fmaxf(m, __shfl_xor(m, off, F));

    float selfw = __expf(selft - m);
    float l = (lane == 0) ? selfw : 0.f;
#pragma unroll
    for (int k = 0; k < K; ++k) {
        int j = k * F + lane;
        if (j < deg) {
            float e = __expf(wreg[k] - m);
            wldsg[j] = e;
            l += e;
        }
    }
    for (int j = NS + lane; j < deg; j += F)
        l += __expf(llrelu(Ssrc[esrc[rs + j]] + sdi) - m);
#pragma unroll
    for (int off = F / 2; off > 0; off >>= 1) l += __shfl_xor(l, off, F);
    float winv = 1.f / l;

    // pass 3: full 16-slot batches + 8-slot tail (deg is wave-uniform ->
    // uniform branch; stash pre-init makes any aligned batch safe).
    float acc = selfw * bf2f(H[(size_t)node * F + lane]);
    int nbv = deg < NS ? deg : NS;
    int nb16 = nbv & ~15;
    int j0 = 0;
    for (; j0 < nb16; j0 += 16) gather_fma<16>(H, wldsg, ildsg, j0, lane, acc);
    int rem = nbv - nb16;
    if (rem > 8) gather_fma<16>(H, wldsg, ildsg, j0, lane, acc);
    else if (rem > 0) gather_fma<8>(H, wldsg, ildsg, j0, lane, acc);

    for (int j = NS; j < deg; ++j) {
        int s = esrc[rs + j];
        float wj = __expf(llrelu(Ssrc[s] + sdi) - m);
        acc = fmaf(wj, bf2f(H[(size_t)s * F + lane]), acc);
    }
    return acc * winv;
}

// Standalone aggregation: one node per group, OUT f32 (+bias optional).
template <int F, int K, bool WITH_BIAS>
__global__ void gat_aggr_kernel(const unsigned short* __restrict__ H,
                                const float* __restrict__ Ssrc, const float* __restrict__ Sdst,
                                const int* __restrict__ rowst, const int* __restrict__ esrc,
                                const float* __restrict__ bias, float* __restrict__ OUT, int n) {
    constexpr int GPB = BLOCK / F;
    __shared__ __align__(16) float wlds[GPB][K * F];
    __shared__ __align__(16) int ilds[GPB][K * F];
    int tid = threadIdx.x;
    int grp = tid / F, lane = tid % F;
    int node = blockIdx.x * GPB + grp;
    if (node >= n) return;
    float acc = aggr_node_core<F, K>(H, Ssrc, Sdst, rowst, esrc, node, lane,
                                     wlds[grp], ilds[grp]);
    if (WITH_BIAS) acc += bias[lane];
    OUT[(size_t)node * F + lane] = acc;
}

// Sum OUT3 over nodes into facc[32].
__global__ void mean_kernel(const float* __restrict__ B, float* __restrict__ facc, int n) {
    __shared__ float s[32];
    int lane = threadIdx.x & 31, row = threadIdx.x >> 5;
    float a = 0.f;
    for (int node = blockIdx.x * 8 + row; node < n; node += gridDim.x * 8)
        a += B[(size_t)node * 32 + lane];
    if (threadIdx.x < 32) s[threadIdx.x] = 0.f;
    __syncthreads();
    atomicAdd(&s[lane], a);
    __syncthreads();
    if (threadIdx.x < 32) atomicAdd(&facc[threadIdx.x], s[threadIdx.x]);
}

__global__ void finalize_kernel(const float* __restrict__ facc, const float* __restrict__ b,
                                const float* __restrict__ tdp, const float* __restrict__ cansup,
                                float* __restrict__ out, int n) {
    int f = threadIdx.x;
    if (f < 32) {
        float td = tdp[0] * cansup[0];
        out[f] = (facc[f] / (float)n + b[f]) * td;
    }
}

extern "C" void kernel_launch(void* const* d_in, const int* in_sizes, int n_in,
                              void* d_out, int out_size, void* d_ws, size_t ws_size,
                              hipStream_t stream) {
    const float* x      = (const float*)d_in[0];
    const int* eidx     = (const int*)d_in[1];
    const float* W1     = (const float*)d_in[2];
    const float* as1    = (const float*)d_in[3];
    const float* ad1    = (const float*)d_in[4];
    const float* b1     = (const float*)d_in[5];
    const float* W2     = (const float*)d_in[6];
    const float* as2    = (const float*)d_in[7];
    const float* ad2    = (const float*)d_in[8];
    const float* b2     = (const float*)d_in[9];
    const float* W3     = (const float*)d_in[10];
    const float* as3    = (const float*)d_in[11];
    const float* ad3    = (const float*)d_in[12];
    const float* b3     = (const float*)d_in[13];
    const float* tdp    = (const float*)d_in[14];
    const float* cansup = (const float*)d_in[15];

    const int n = in_sizes[0] / 64;   // 100000 nodes
    const int E = in_sizes[1] / 2;    // 1600000 edges
    const int* srcp = eidx;
    const int* dstp = eidx + E;

    const int NB = (n + 63) >> BSH;           // 1563 buckets
    const int chunk = (E + NBLK - 1) / NBLK;  // edges per hist/scatter block
    const int total = NB * NBLK;              // scan matrix size

    char* ws = (char*)d_ws;
    size_t off = 0;
    auto alloc = [&](size_t bytes) -> void* {
        void* p = ws + off;
        off += (bytes + 255) & ~(size_t)255;
        return p;
    };
    unsigned short* H1 = (unsigned short*)alloc((size_t)n * 64 * sizeof(unsigned short));
    unsigned short* H2 = (unsigned short*)alloc((size_t)n * 32 * sizeof(unsigned short));
    unsigned short* H3 = (unsigned short*)alloc((size_t)n * 32 * sizeof(unsigned short));
    float* B      = (float*)alloc((size_t)n * 64 * sizeof(float));  // f32 layer output
    float* ssA    = (float*)alloc((size_t)n * sizeof(float));
    float* sdA    = (float*)alloc((size_t)n * sizeof(float));
    float* ssB    = (float*)alloc((size_t)n * sizeof(float));
    float* sdB    = (float*)alloc((size_t)n * sizeof(float));
    float* ssC    = (float*)alloc((size_t)n * sizeof(float));
    float* sdC    = (float*)alloc((size_t)n * sizeof(float));
    int*   S      = (int*)alloc((size_t)total * sizeof(int));
    int*   bsums  = (int*)alloc(1024 * sizeof(int));
    int*   rowst  = (int*)alloc((size_t)(n + 1) * sizeof(int));
    int*   esrc   = (int*)alloc((size_t)E * sizeof(int));
    int*   pairs  = (int*)alloc((size_t)E * sizeof(int));
    float* facc   = (float*)alloc(64 * sizeof(float));

    // ---- CSR build (counting sort, no global atomics) + layer-1 GEMM ----
    const int ngemm1 = (n + 63) / 64;
    const int gmax = (ngemm1 > NBLK) ? ngemm1 : NBLK;
    hist_gemm1_kernel<<<2 * gmax, BLOCK, 0, stream>>>(
        x, W1, as1, ad1, H1, ssA, sdA, n, ngemm1, dstp, E, chunk, NB, S, facc);
    int nb1 = (total + 1023) / 1024;
    scan1_kernel<<<nb1, 1024, 0, stream>>>(S, total, bsums);
    scan2_kernel<<<1, 1024, 0, stream>>>(bsums, nb1);
    scan3_kernel<<<(total + 255) / 256, 256, 0, stream>>>(S, bsums, total);
    scatter_kernel<<<NBLK, BLOCK, 0, stream>>>(srcp, dstp, E, chunk, NB, S, pairs);
    bucket_csr_kernel<<<NB, BLOCK, 0, stream>>>(pairs, S, NB, n, E, rowst, esrc);

    // ---- layer 1 aggregation ----
    gat_aggr_kernel<64, 2, true><<<(n + 3) / 4, BLOCK, 0, stream>>>(
        H1, ssA, sdA, rowst, esrc, b1, B, n);

    // ---- layer 2 ----
    gemm_att_kernel<64, 32, true><<<(n + 127) / 128, BLOCK, 0, stream>>>(
        B, W2, as2, ad2, H2, ssB, sdB, n);
    gat_aggr_kernel<32, 4, true><<<(n + 7) / 8, BLOCK, 0, stream>>>(
        H2, ssB, sdB, rowst, esrc, b2, B, n);

    // ---- layer 3 ----
    gemm_att_kernel<32, 32, true><<<(n + 127) / 128, BLOCK, 0, stream>>>(
        B, W3, as3, ad3, H3, ssC, sdC, n);
    gat_aggr_kernel<32, 4, false><<<(n + 7) / 8, BLOCK, 0, stream>>>(
        H3, ssC, sdC, rowst, esrc, nullptr, B, n);
    mean_kernel<<<1024, 256, 0, stream>>>(B, facc, n);
    finalize_kernel<<<1, 64, 0, stream>>>(facc, b3, tdp, cansup, (float*)d_out, n);
}

// Round 14
// 215.101 us; speedup vs baseline: 1.1369x; 1.0783x over previous
//
#include <hip/hip_runtime.h>

// 3-layer GAT (PyG GATConv) on MI355X.
// CSR build via two-level counting sort — NO global atomics:
//   A: per-block LDS histogram over coarse buckets (64 nodes each),
//      layer-1 GEMM rides on even blocks (heterogeneous, LDS union).
//   scan: 3-pass exclusive scan of the (bucket x block) matrix.
//   C: re-read chunk, LDS returning-atomic cursors -> scatter PACKED
//      (src | (dst&63)<<17) 4-byte records into bucket regions.
//   D: one block per bucket: LDS 64-hist + scan -> rowst + esrc.
// NBLK=512 (R12 lesson: 1024 doubles scan-matrix + hist overhead).
// Layers: gemm_att (micro-tiled LDS GEMM, bf16 H epilogue) -> gat_aggr
// (fused softmax + gather; R14: each lane owns TWO adjacent bf16 columns
// via u32 loads — halves gather VMEM instrs, cuts addressing VALU ~35%;
// F/2 lanes per node, 2-4 nodes per wave, exact bit-identical unpack).

constexpr int BLOCK = 256;
constexpr int NBLK = 512;    // hist/scatter blocks (chunked edge ownership)
constexpr int BSH = 6;       // 64 nodes per bucket
constexpr int MAXNB = 1600;  // max buckets (n <= 102400)

__device__ __forceinline__ float llrelu(float x) { return x >= 0.f ? x : 0.2f * x; }

__device__ __forceinline__ unsigned short f2bf(float f) {
    unsigned int u = __float_as_uint(f);
    u += 0x7FFFu + ((u >> 16) & 1u);  // round-to-nearest-even
    return (unsigned short)(u >> 16);
}
__device__ __forceinline__ float bf2f(unsigned short h) {
    return __uint_as_float((unsigned int)h << 16);
}

// ---------- GEMM body (H bf16 + attention dots), LDS provided by caller ----------
template <int FIN, int FOUT, bool RELU_IN>
__device__ __forceinline__ void gemm_att_body(
    const float* __restrict__ X, const float* __restrict__ W,
    const float* __restrict__ asrc, const float* __restrict__ adst,
    unsigned short* __restrict__ H, float* __restrict__ Ssrc,
    float* __restrict__ Sdst, int n, int gblk, float* Xs, float* Ws) {
    constexpr int CG = FOUT / 4;
    constexpr int NG = BLOCK / CG;
    constexpr int TN = NG * 4;
    constexpr int S = FIN + 4;

    int tid = threadIdx.x;
    int n0_blk = gblk * TN;

    for (int t = tid; t < FIN * FOUT / 4; t += BLOCK) {
        float4 v = ((const float4*)W)[t];
        *(float4*)&Ws[t * 4] = v;
    }
    constexpr int RW = FIN / 4;
    for (int t = tid; t < TN * RW; t += BLOCK) {
        int r = t / RW, c = t % RW;
        int gr = n0_blk + r;
        if (gr >= n) gr = n - 1;
        float4 v = ((const float4*)(X + (size_t)gr * FIN))[c];
        if (RELU_IN) {
            v.x = fmaxf(v.x, 0.f); v.y = fmaxf(v.y, 0.f);
            v.z = fmaxf(v.z, 0.f); v.w = fmaxf(v.w, 0.f);
        }
        *(float4*)&Xs[r * S + c * 4] = v;
    }
    __syncthreads();

    int tx = tid % CG, ty = tid / CG;
    int c0 = tx * 4, nloc = ty * 4;

    float acc[4][4];
#pragma unroll
    for (int i = 0; i < 4; ++i)
#pragma unroll
        for (int j = 0; j < 4; ++j) acc[i][j] = 0.f;

#pragma unroll 2
    for (int kc = 0; kc < FIN / 4; ++kc) {
        float4 xv[4], wv[4];
#pragma unroll
        for (int i = 0; i < 4; ++i) xv[i] = *(const float4*)&Xs[(nloc + i) * S + kc * 4];
#pragma unroll
        for (int kk = 0; kk < 4; ++kk) wv[kk] = *(const float4*)&Ws[(kc * 4 + kk) * FOUT + c0];
#pragma unroll
        for (int i = 0; i < 4; ++i) {
            float xi0 = xv[i].x, xi1 = xv[i].y, xi2 = xv[i].z, xi3 = xv[i].w;
            acc[i][0] = fmaf(xi0, wv[0].x, acc[i][0]);
            acc[i][1] = fmaf(xi0, wv[0].y, acc[i][1]);
            acc[i][2] = fmaf(xi0, wv[0].z, acc[i][2]);
            acc[i][3] = fmaf(xi0, wv[0].w, acc[i][3]);
            acc[i][0] = fmaf(xi1, wv[1].x, acc[i][0]);
            acc[i][1] = fmaf(xi1, wv[1].y, acc[i][1]);
            acc[i][2] = fmaf(xi1, wv[1].z, acc[i][2]);
            acc[i][3] = fmaf(xi1, wv[1].w, acc[i][3]);
            acc[i][0] = fmaf(xi2, wv[2].x, acc[i][0]);
            acc[i][1] = fmaf(xi2, wv[2].y, acc[i][1]);
            acc[i][2] = fmaf(xi2, wv[2].z, acc[i][2]);
            acc[i][3] = fmaf(xi2, wv[2].w, acc[i][3]);
            acc[i][0] = fmaf(xi3, wv[3].x, acc[i][0]);
            acc[i][1] = fmaf(xi3, wv[3].y, acc[i][1]);
            acc[i][2] = fmaf(xi3, wv[3].z, acc[i][2]);
            acc[i][3] = fmaf(xi3, wv[3].w, acc[i][3]);
        }
    }

    float4 as4 = *(const float4*)&asrc[c0];
    float4 ad4 = *(const float4*)&adst[c0];

#pragma unroll
    for (int i = 0; i < 4; ++i) {
        int node = n0_blk + nloc + i;
        bool ok = node < n;
        if (ok) {
            ushort4 hb;
            hb.x = f2bf(acc[i][0]); hb.y = f2bf(acc[i][1]);
            hb.z = f2bf(acc[i][2]); hb.w = f2bf(acc[i][3]);
            *(ushort4*)&H[(size_t)node * FOUT + c0] = hb;
        }
        float vs = acc[i][0] * as4.x + acc[i][1] * as4.y + acc[i][2] * as4.z + acc[i][3] * as4.w;
        float vd = acc[i][0] * ad4.x + acc[i][1] * ad4.y + acc[i][2] * ad4.z + acc[i][3] * ad4.w;
#pragma unroll
        for (int off = CG / 2; off > 0; off >>= 1) {
            vs += __shfl_xor(vs, off, CG);
            vd += __shfl_xor(vd, off, CG);
        }
        if (tx == 0 && ok) {
            Ssrc[node] = vs;
            Sdst[node] = vd;
        }
    }
}

template <int FIN, int FOUT, bool RELU_IN>
__global__ void gemm_att_kernel(const float* __restrict__ X, const float* __restrict__ W,
                                const float* __restrict__ asrc, const float* __restrict__ adst,
                                unsigned short* __restrict__ H, float* __restrict__ Ssrc,
                                float* __restrict__ Sdst, int n) {
    constexpr int CG = FOUT / 4;
    constexpr int NG = BLOCK / CG;
    constexpr int TN = NG * 4;
    constexpr int S = FIN + 4;
    __shared__ float Xs[TN * S];
    __shared__ float Ws[FIN * FOUT];
    gemm_att_body<FIN, FOUT, RELU_IN>(X, W, asrc, adst, H, Ssrc, Sdst, n, blockIdx.x, Xs, Ws);
}

// ---------- Phase A: coarse histogram (odd blocks) + layer-1 GEMM (even) ----------
__global__ void hist_gemm1_kernel(const float* __restrict__ X, const float* __restrict__ W,
                                  const float* __restrict__ asrc, const float* __restrict__ adst,
                                  unsigned short* __restrict__ H, float* __restrict__ Ssrc,
                                  float* __restrict__ Sdst, int n, int ngemm,
                                  const int* __restrict__ dst, int E, int chunk, int NB,
                                  int* __restrict__ S, float* __restrict__ facc) {
    // LDS union: gemm<64,64> needs 64*68 + 64*64 = 8448 floats; hist needs 1600 ints.
    __shared__ __align__(16) float lds[8448];
    int bid = blockIdx.x;
    if ((bid & 1) == 0) {
        int gb = bid >> 1;
        if (gb >= ngemm) return;
        gemm_att_body<64, 64, false>(X, W, asrc, adst, H, Ssrc, Sdst, n, gb, lds, lds + 64 * 68);
    } else {
        int k = bid >> 1;
        if (k >= NBLK) return;
        int* hist = (int*)lds;
        for (int i = threadIdx.x; i < NB; i += BLOCK) hist[i] = 0;
        if (k == 0 && threadIdx.x < 32) facc[threadIdx.x] = 0.f;
        __syncthreads();
        int start = k * chunk, end = min(E, start + chunk);
        for (int i = start + threadIdx.x; i < end; i += BLOCK)
            atomicAdd(&hist[dst[i] >> BSH], 1);
        __syncthreads();
        for (int b = threadIdx.x; b < NB; b += BLOCK) S[(size_t)b * NBLK + k] = hist[b];
    }
}

// ---------- 3-pass exclusive scan over S[NB*NBLK] ----------
__global__ void scan1_kernel(int* __restrict__ S, int total, int* __restrict__ bsums) {
    __shared__ int s[1024];
    int tid = threadIdx.x;
    int gid = blockIdx.x * 1024 + tid;
    int v = (gid < total) ? S[gid] : 0;
    s[tid] = v;
    for (int off = 1; off < 1024; off <<= 1) {
        __syncthreads();
        int t = (tid >= off) ? s[tid - off] : 0;
        __syncthreads();
        s[tid] += t;
    }
    __syncthreads();
    if (gid < total) S[gid] = s[tid] - v;  // exclusive within block
    if (tid == 1023) bsums[blockIdx.x] = s[tid];
}

// Single-block tiled scan (handles nb > 1024 via carried offset).
__global__ void scan2_kernel(int* __restrict__ bsums, int nb) {
    __shared__ int s[1024];
    __shared__ int carry_s;
    int tid = threadIdx.x;
    if (tid == 0) carry_s = 0;
    __syncthreads();
    for (int base = 0; base < nb; base += 1024) {
        int i = base + tid;
        int v = (i < nb) ? bsums[i] : 0;
        s[tid] = v;
        for (int off = 1; off < 1024; off <<= 1) {
            __syncthreads();
            int t = (tid >= off) ? s[tid - off] : 0;
            __syncthreads();
            s[tid] += t;
        }
        __syncthreads();
        int c = carry_s;
        if (i < nb) bsums[i] = s[tid] - v + c;  // exclusive + carry
        __syncthreads();
        if (tid == 1023) carry_s = c + s[1023];
        __syncthreads();
    }
}

__global__ void scan3_kernel(int* __restrict__ S, const int* __restrict__ bsums, int total) {
    int gid = blockIdx.x * blockDim.x + threadIdx.x;
    if (gid < total) S[gid] += bsums[gid >> 10];
}

// ---------- Phase C: scatter packed records into bucket regions ----------
// Record: src | (dst&63)<<17  (requires n <= 131072; here n = 100000).
__global__ void scatter_kernel(const int* __restrict__ src, const int* __restrict__ dst,
                               int E, int chunk, int NB, const int* __restrict__ S,
                               int* __restrict__ pairs) {
    __shared__ int cursor[MAXNB];
    int k = blockIdx.x;
    for (int b = threadIdx.x; b < NB; b += BLOCK) cursor[b] = S[(size_t)b * NBLK + k];
    __syncthreads();
    int start = k * chunk, end = min(E, start + chunk);
    for (int i = start + threadIdx.x; i < end; i += BLOCK) {
        int d = dst[i], s = src[i];
        int pos = atomicAdd(&cursor[d >> BSH], 1);  // LDS returning atomic
        pairs[pos] = s | ((d & 63) << 17);
    }
}

// ---------- Phase D: per-bucket CSR (rowst + in-bucket dst-sorted esrc) ----------
__global__ void bucket_csr_kernel(const int* __restrict__ pairs, const int* __restrict__ S,
                                  int NB, int n, int E, int* __restrict__ rowst,
                                  int* __restrict__ esrc) {
    __shared__ int cnt[64], excl[64];
    int b = blockIdx.x;
    if (b >= NB) return;
    int base = S[(size_t)b * NBLK];
    int end = (b + 1 < NB) ? S[(size_t)(b + 1) * NBLK] : E;
    int m = end - base;
    if (threadIdx.x < 64) cnt[threadIdx.x] = 0;
    __syncthreads();
    for (int i = threadIdx.x; i < m; i += BLOCK)
        atomicAdd(&cnt[pairs[base + i] >> 17], 1);
    __syncthreads();
    if (threadIdx.x == 0) {
        int run = 0;
        for (int j = 0; j < 64; ++j) { excl[j] = run; run += cnt[j]; }
    }
    __syncthreads();
    int node0 = b << BSH;
    if (threadIdx.x < 64) {
        int node = node0 + threadIdx.x;
        if (node < n) rowst[node] = base + excl[threadIdx.x];
        cnt[threadIdx.x] = excl[threadIdx.x];  // becomes the running cursor
    }
    if (b == NB - 1 && threadIdx.x == 0) rowst[n] = E;
    __syncthreads();
    for (int i = threadIdx.x; i < m; i += BLOCK) {
        int p = pairs[base + i];
        int pos = atomicAdd(&cnt[p >> 17], 1);  // LDS returning atomic
        esrc[base + pos] = p & 0x1FFFF;
    }
}

// ---------- dual-column gather-FMA batch (NBATCH stash slots) ----------
// Each lane loads ONE u32 (two adjacent bf16 columns) per slot; exact unpack.
template <int NBATCH>
__device__ __forceinline__ void gather_fma2(const unsigned int* __restrict__ Hu,
                                            const float* wldsg, const int* ildsg,
                                            int j0, int lane, float& acc0, float& acc1) {
    float wv[NBATCH];
    int ix[NBATCH];
#pragma unroll
    for (int q = 0; q < NBATCH / 4; ++q) {
        float4 w = *(const float4*)&wldsg[j0 + q * 4];
        int4 i4 = *(const int4*)&ildsg[j0 + q * 4];
        wv[q * 4 + 0] = w.x; wv[q * 4 + 1] = w.y; wv[q * 4 + 2] = w.z; wv[q * 4 + 3] = w.w;
        ix[q * 4 + 0] = i4.x; ix[q * 4 + 1] = i4.y; ix[q * 4 + 2] = i4.z; ix[q * 4 + 3] = i4.w;
    }
    unsigned int pv[NBATCH];
#pragma unroll
    for (int u = 0; u < NBATCH; ++u) pv[u] = Hu[(size_t)(unsigned)(ix[u] + lane)];
#pragma unroll
    for (int u = 0; u < NBATCH; ++u) {
        acc0 = fmaf(wv[u], __uint_as_float(pv[u] << 16), acc0);
        acc1 = fmaf(wv[u], __uint_as_float(pv[u] & 0xFFFF0000u), acc1);
    }
}

// ---------- fused softmax + gather core (2 columns per lane) ----------
// LPN = F/2 lanes serve one node; lane owns columns {2*lane, 2*lane+1}.
template <int F, int K>
__device__ __forceinline__ float2 aggr_node_core(
    const unsigned short* __restrict__ H, const float* __restrict__ Ssrc,
    const float* __restrict__ Sdst, const int* __restrict__ row_start,
    const int* __restrict__ esrc, int node, int lane,
    float* wldsg, int* ildsg) {
    constexpr int LPN = F / 2;
    constexpr int NS = K * LPN;
    const unsigned int* Hu = (const unsigned int*)H;
    int rs = row_start[node];
    int deg = row_start[node + 1] - rs;
    float sdi = Sdst[node];
    float selft = llrelu(Ssrc[node] + sdi);

    float wreg[K];
#pragma unroll
    for (int k = 0; k < K; ++k) {
        wldsg[k * LPN + lane] = 0.f;
        ildsg[k * LPN + lane] = node * LPN;  // u32-offset of own row (safe tail)
    }

    float m = selft;
#pragma unroll
    for (int k = 0; k < K; ++k) {
        int j = k * LPN + lane;
        if (j < deg) {
            int s = esrc[rs + j];
            float t = llrelu(Ssrc[s] + sdi);
            ildsg[j] = s * LPN;
            wreg[k] = t;
            m = fmaxf(m, t);
        }
    }
    for (int j = NS + lane; j < deg; j += LPN)
        m = fmaxf(m, llrelu(Ssrc[esrc[rs + j]] + sdi));
#pragma unroll
    for (int off = LPN / 2; off > 0; off >>= 1) m = fmaxf(m, __shfl_xor(m, off, LPN));

    float selfw = __expf(selft - m);
    float l = (lane == 0) ? selfw : 0.f;
#pragma unroll
    for (int k = 0; k < K; ++k) {
        int j = k * LPN + lane;
        if (j < deg) {
            float e = __expf(wreg[k] - m);
            wldsg[j] = e;
            l += e;
        }
    }
    for (int j = NS + lane; j < deg; j += LPN)
        l += __expf(llrelu(Ssrc[esrc[rs + j]] + sdi) - m);
#pragma unroll
    for (int off = LPN / 2; off > 0; off >>= 1) l += __shfl_xor(l, off, LPN);
    float winv = 1.f / l;

    // pass 3: full 16-slot batches + 8-slot tail (uniform per group).
    unsigned int pself = Hu[(size_t)node * LPN + lane];
    float acc0 = selfw * __uint_as_float(pself << 16);
    float acc1 = selfw * __uint_as_float(pself & 0xFFFF0000u);
    int nbv = deg < NS ? deg : NS;
    int nb16 = nbv & ~15;
    int j0 = 0;
    for (; j0 < nb16; j0 += 16) gather_fma2<16>(Hu, wldsg, ildsg, j0, lane, acc0, acc1);
    int rem = nbv - nb16;
    if (rem > 8) gather_fma2<16>(Hu, wldsg, ildsg, j0, lane, acc0, acc1);
    else if (rem > 0) gather_fma2<8>(Hu, wldsg, ildsg, j0, lane, acc0, acc1);

    for (int j = NS; j < deg; ++j) {  // overflow: recompute w_j (rare)
        int s = esrc[rs + j];
        float wj = __expf(llrelu(Ssrc[s] + sdi) - m);
        unsigned int p = Hu[(size_t)s * LPN + lane];
        acc0 = fmaf(wj, __uint_as_float(p << 16), acc0);
        acc1 = fmaf(wj, __uint_as_float(p & 0xFFFF0000u), acc1);
    }
    return make_float2(acc0 * winv, acc1 * winv);
}

// Standalone aggregation: LPN=F/2 lanes per node, float2 output per lane.
template <int F, int K, bool WITH_BIAS>
__global__ void gat_aggr_kernel(const unsigned short* __restrict__ H,
                                const float* __restrict__ Ssrc, const float* __restrict__ Sdst,
                                const int* __restrict__ rowst, const int* __restrict__ esrc,
                                const float* __restrict__ bias, float* __restrict__ OUT, int n) {
    constexpr int LPN = F / 2;
    constexpr int GPB = BLOCK / LPN;
    __shared__ __align__(16) float wlds[GPB][K * LPN];
    __shared__ __align__(16) int ilds[GPB][K * LPN];
    int tid = threadIdx.x;
    int grp = tid / LPN, lane = tid % LPN;
    int node = blockIdx.x * GPB + grp;
    if (node >= n) return;
    float2 acc = aggr_node_core<F, K>(H, Ssrc, Sdst, rowst, esrc, node, lane,
                                      wlds[grp], ilds[grp]);
    if (WITH_BIAS) {
        float2 bb = *(const float2*)&bias[2 * lane];
        acc.x += bb.x;
        acc.y += bb.y;
    }
    *(float2*)&OUT[(size_t)node * F + 2 * lane] = acc;
}

// Sum OUT3 over nodes into facc[32].
__global__ void mean_kernel(const float* __restrict__ B, float* __restrict__ facc, int n) {
    __shared__ float s[32];
    int lane = threadIdx.x & 31, row = threadIdx.x >> 5;
    float a = 0.f;
    for (int node = blockIdx.x * 8 + row; node < n; node += gridDim.x * 8)
        a += B[(size_t)node * 32 + lane];
    if (threadIdx.x < 32) s[threadIdx.x] = 0.f;
    __syncthreads();
    atomicAdd(&s[lane], a);
    __syncthreads();
    if (threadIdx.x < 32) atomicAdd(&facc[threadIdx.x], s[threadIdx.x]);
}

__global__ void finalize_kernel(const float* __restrict__ facc, const float* __restrict__ b,
                                const float* __restrict__ tdp, const float* __restrict__ cansup,
                                float* __restrict__ out, int n) {
    int f = threadIdx.x;
    if (f < 32) {
        float td = tdp[0] * cansup[0];
        out[f] = (facc[f] / (float)n + b[f]) * td;
    }
}

extern "C" void kernel_launch(void* const* d_in, const int* in_sizes, int n_in,
                              void* d_out, int out_size, void* d_ws, size_t ws_size,
                              hipStream_t stream) {
    const float* x      = (const float*)d_in[0];
    const int* eidx     = (const int*)d_in[1];
    const float* W1     = (const float*)d_in[2];
    const float* as1    = (const float*)d_in[3];
    const float* ad1    = (const float*)d_in[4];
    const float* b1     = (const float*)d_in[5];
    const float* W2     = (const float*)d_in[6];
    const float* as2    = (const float*)d_in[7];
    const float* ad2    = (const float*)d_in[8];
    const float* b2     = (const float*)d_in[9];
    const float* W3     = (const float*)d_in[10];
    const float* as3    = (const float*)d_in[11];
    const float* ad3    = (const float*)d_in[12];
    const float* b3     = (const float*)d_in[13];
    const float* tdp    = (const float*)d_in[14];
    const float* cansup = (const float*)d_in[15];

    const int n = in_sizes[0] / 64;   // 100000 nodes
    const int E = in_sizes[1] / 2;    // 1600000 edges
    const int* srcp = eidx;
    const int* dstp = eidx + E;

    const int NB = (n + 63) >> BSH;           // 1563 buckets
    const int chunk = (E + NBLK - 1) / NBLK;  // edges per hist/scatter block
    const int total = NB * NBLK;              // scan matrix size

    char* ws = (char*)d_ws;
    size_t off = 0;
    auto alloc = [&](size_t bytes) -> void* {
        void* p = ws + off;
        off += (bytes + 255) & ~(size_t)255;
        return p;
    };
    unsigned short* H1 = (unsigned short*)alloc((size_t)n * 64 * sizeof(unsigned short));
    unsigned short* H2 = (unsigned short*)alloc((size_t)n * 32 * sizeof(unsigned short));
    unsigned short* H3 = (unsigned short*)alloc((size_t)n * 32 * sizeof(unsigned short));
    float* B      = (float*)alloc((size_t)n * 64 * sizeof(float));  // f32 layer output
    float* ssA    = (float*)alloc((size_t)n * sizeof(float));
    float* sdA    = (float*)alloc((size_t)n * sizeof(float));
    float* ssB    = (float*)alloc((size_t)n * sizeof(float));
    float* sdB    = (float*)alloc((size_t)n * sizeof(float));
    float* ssC    = (float*)alloc((size_t)n * sizeof(float));
    float* sdC    = (float*)alloc((size_t)n * sizeof(float));
    int*   S      = (int*)alloc((size_t)total * sizeof(int));
    int*   bsums  = (int*)alloc(1024 * sizeof(int));
    int*   rowst  = (int*)alloc((size_t)(n + 1) * sizeof(int));
    int*   esrc   = (int*)alloc((size_t)E * sizeof(int));
    int*   pairs  = (int*)alloc((size_t)E * sizeof(int));
    float* facc   = (float*)alloc(64 * sizeof(float));

    // ---- CSR build (counting sort, no global atomics) + layer-1 GEMM ----
    const int ngemm1 = (n + 63) / 64;
    const int gmax = (ngemm1 > NBLK) ? ngemm1 : NBLK;
    hist_gemm1_kernel<<<2 * gmax, BLOCK, 0, stream>>>(
        x, W1, as1, ad1, H1, ssA, sdA, n, ngemm1, dstp, E, chunk, NB, S, facc);
    int nb1 = (total + 1023) / 1024;
    scan1_kernel<<<nb1, 1024, 0, stream>>>(S, total, bsums);
    scan2_kernel<<<1, 1024, 0, stream>>>(bsums, nb1);
    scan3_kernel<<<(total + 255) / 256, 256, 0, stream>>>(S, bsums, total);
    scatter_kernel<<<NBLK, BLOCK, 0, stream>>>(srcp, dstp, E, chunk, NB, S, pairs);
    bucket_csr_kernel<<<NB, BLOCK, 0, stream>>>(pairs, S, NB, n, E, rowst, esrc);

    // ---- layer 1 aggregation (32 lanes/node, 8 nodes/block) ----
    gat_aggr_kernel<64, 4, true><<<(n + 7) / 8, BLOCK, 0, stream>>>(
        H1, ssA, sdA, rowst, esrc, b1, B, n);

    // ---- layer 2 ----
    gemm_att_kernel<64, 32, true><<<(n + 127) / 128, BLOCK, 0, stream>>>(
        B, W2, as2, ad2, H2, ssB, sdB, n);
    gat_aggr_kernel<32, 8, true><<<(n + 15) / 16, BLOCK, 0, stream>>>(
        H2, ssB, sdB, rowst, esrc, b2, B, n);

    // ---- layer 3 ----
    gemm_att_kernel<32, 32, true><<<(n + 127) / 128, BLOCK, 0, stream>>>(
        B, W3, as3, ad3, H3, ssC, sdC, n);
    gat_aggr_kernel<32, 8, false><<<(n + 15) / 16, BLOCK, 0, stream>>>(
        H3, ssC, sdC, rowst, esrc, nullptr, B, n);
    mean_kernel<<<1024, 256, 0, stream>>>(B, facc, n);
    finalize_kernel<<<1, 64, 0, stream>>>(facc, b3, tdp, cansup, (float*)d_out, n);
}